// Round 1
// baseline (468.863 us; speedup 1.0000x reference)
//
#include <hip/hip_runtime.h>
#include <math.h>

#define N_PTS   8192
#define NBATCH  4
#define NQ      (N_PTS*NBATCH)   // 32768
#define GFN     100
#define KNN     10
#define NSPLIT  4
#define SPLITL  (N_PTS/NSPLIT)   // 2048

__device__ __forceinline__ float med3f(float a, float b, float c){
  return __builtin_amdgcn_fmed3f(a, b, c);
}

// sorted insert of d into ascending m[0..9], dropping the largest.
// m[k] = median(d, m[k-1], m[k]) == min(m[k], max(d, m[k-1])) for sorted m.
__device__ __forceinline__ void insert10(float (&m)[KNN], float d){
  #pragma unroll
  for (int k = KNN-1; k > 0; k--) m[k] = med3f(d, m[k-1], m[k]);
  m[0] = fminf(m[0], d);
}

__global__ void zero_kernel(float* __restrict__ pool){
  int i = blockIdx.x * 64 + threadIdx.x;
  if (i < NBATCH * GFN) pool[i] = 0.0f;
}

// ---------------- K1: KNN top-10 distances, 4-way split over j ----------------
__global__ __launch_bounds__(256) void knn_kernel(const float* __restrict__ x,
                                                  float* __restrict__ cand){
  __shared__ float4 tile[SPLITL];   // 32 KB: (x,y,z,sq) per staged point
  const int t  = threadIdx.x;
  const int qb = blockIdx.x;        // 0..127 query blocks
  const int s  = blockIdx.y;        // 0..3 j-splits
  const int q  = qb * 256 + t;      // global point id
  const int b  = q >> 13;           // batch (8192 pts/batch)
  const float* xb = x + (size_t)b * N_PTS * 3;

  // Stage this split's 2048 points: 6144 floats = 1536 float4, 6 per thread.
  {
    const float4* src = reinterpret_cast<const float4*>(xb + (size_t)s * SPLITL * 3);
    float f[24];
    #pragma unroll
    for (int k = 0; k < 6; k++){
      float4 v = src[t*6 + k];
      f[4*k+0] = v.x; f[4*k+1] = v.y; f[4*k+2] = v.z; f[4*k+3] = v.w;
    }
    #pragma unroll
    for (int p = 0; p < 8; p++){
      float px = f[3*p+0], py = f[3*p+1], pz = f[3*p+2];
      float sq = fmaf(pz, pz, fmaf(py, py, px*px));
      tile[t*8 + p] = make_float4(px, py, pz, sq);
    }
  }
  __syncthreads();

  // Query point (same formula as staging so self-distance is exactly 0).
  const float xi = x[(size_t)q*3+0], yi = x[(size_t)q*3+1], zi = x[(size_t)q*3+2];
  const float sqi = fmaf(zi, zi, fmaf(yi, yi, xi*xi));

  float m[KNN];
  #pragma unroll
  for (int k = 0; k < KNN; k++) m[k] = INFINITY;

  #pragma unroll 4
  for (int j = 0; j < SPLITL; j++){
    float4 p = tile[j];
    float dot = fmaf(zi, p.z, fmaf(yi, p.y, xi*p.x));
    float d   = fmaf(-2.0f, dot, sqi + p.w);   // sq_i + sq_j - 2*dot
    if (d < m[KNN-1]) insert10(m, d);
  }

  float* outp = cand + (size_t)q * (NSPLIT*KNN) + s * KNN;
  #pragma unroll
  for (int k = 0; k < KNN; k++) outp[k] = m[k];
}

// ------------- K2: merge top-10, conv1 (13->20->100), conv2 (100->100) + pool -------------
__global__ __launch_bounds__(256) void mlp1_kernel(
    const float* __restrict__ x,   const float* __restrict__ cand,
    const float* __restrict__ w1a, const float* __restrict__ b1a,
    const float* __restrict__ w1b, const float* __restrict__ b1b,
    const float* __restrict__ w2,  const float* __restrict__ b2,
    float* __restrict__ x1t, float* __restrict__ pool){
  __shared__ float t20lds[256*21];   // padded (21 odd => conflict-free)
  const int t = threadIdx.x;
  const int q = blockIdx.x * 256 + t;
  const int b = q >> 13;
  const int lane = t & 63;

  // merge 4 sorted candidate lists -> global top-10 (ascending)
  float m[KNN];
  #pragma unroll
  for (int k = 0; k < KNN; k++) m[k] = INFINITY;
  const float* cp = cand + (size_t)q * (NSPLIT*KNN);
  for (int i = 0; i < NSPLIT*KNN; i++){
    float d = cp[i];
    insert10(m, d);
  }

  // h = [x, topk]  (13)
  float h[13];
  h[0] = x[(size_t)q*3+0]; h[1] = x[(size_t)q*3+1]; h[2] = x[(size_t)q*3+2];
  #pragma unroll
  for (int k = 0; k < KNN; k++) h[3+k] = m[k];

  // t20 = relu(h @ w1a + b1a) -> LDS scratch (dynamic-index safe)
  for (int o = 0; o < 20; o += 4){
    float a0 = b1a[o+0], a1 = b1a[o+1], a2 = b1a[o+2], a3 = b1a[o+3];
    #pragma unroll
    for (int c = 0; c < 13; c++){
      float hv = h[c];
      a0 = fmaf(hv, w1a[c*20+o+0], a0);
      a1 = fmaf(hv, w1a[c*20+o+1], a1);
      a2 = fmaf(hv, w1a[c*20+o+2], a2);
      a3 = fmaf(hv, w1a[c*20+o+3], a3);
    }
    t20lds[t*21+o+0] = fmaxf(a0, 0.0f);
    t20lds[t*21+o+1] = fmaxf(a1, 0.0f);
    t20lds[t*21+o+2] = fmaxf(a2, 0.0f);
    t20lds[t*21+o+3] = fmaxf(a3, 0.0f);
  }

  // x1 = relu(t20 @ w1b + b1b)   (100 static registers)
  float x1[GFN];
  #pragma unroll
  for (int o = 0; o < GFN; o++) x1[o] = b1b[o];
  for (int c = 0; c < 20; c++){
    float tv = t20lds[t*21+c];
    #pragma unroll
    for (int o = 0; o < GFN; o++) x1[o] = fmaf(tv, w1b[c*GFN+o], x1[o]);
  }
  #pragma unroll
  for (int o = 0; o < GFN; o++) x1[o] = fmaxf(x1[o], 0.0f);
  // store transposed [c][point] for coalesced reads in the head kernel
  #pragma unroll
  for (int o = 0; o < GFN; o++) x1t[(size_t)o*NQ + q] = x1[o];

  // x2 = relu(x1 @ w2 + b2); pool += x2 (wave reduce + atomic)
  for (int o = 0; o < GFN; o += 4){
    float a0 = b2[o+0], a1 = b2[o+1], a2 = b2[o+2], a3 = b2[o+3];
    #pragma unroll
    for (int c = 0; c < GFN; c++){
      float xv = x1[c];
      a0 = fmaf(xv, w2[c*GFN+o+0], a0);
      a1 = fmaf(xv, w2[c*GFN+o+1], a1);
      a2 = fmaf(xv, w2[c*GFN+o+2], a2);
      a3 = fmaf(xv, w2[c*GFN+o+3], a3);
    }
    a0 = fmaxf(a0, 0.0f); a1 = fmaxf(a1, 0.0f);
    a2 = fmaxf(a2, 0.0f); a3 = fmaxf(a3, 0.0f);
    #pragma unroll
    for (int off = 1; off < 64; off <<= 1){
      a0 += __shfl_xor(a0, off);
      a1 += __shfl_xor(a1, off);
      a2 += __shfl_xor(a2, off);
      a3 += __shfl_xor(a3, off);
    }
    if (lane == 0){
      atomicAdd(&pool[b*GFN+o+0], a0);
      atomicAdd(&pool[b*GFN+o+1], a1);
      atomicAdd(&pool[b*GFN+o+2], a2);
      atomicAdd(&pool[b*GFN+o+3], a3);
    }
  }
}

// ---------------- K3: head (200->20->10->2) + log_softmax ----------------
__global__ __launch_bounds__(256) void head_kernel(
    const float* __restrict__ x1t, const float* __restrict__ pool,
    const float* __restrict__ w3a, const float* __restrict__ b3a,
    const float* __restrict__ w3b, const float* __restrict__ b3b,
    const float* __restrict__ w3c, const float* __restrict__ b3c,
    float* __restrict__ out){
  __shared__ float poolm[GFN];
  __shared__ float poolpart[20];
  const int t = threadIdx.x;
  const int q = blockIdx.x * 256 + t;
  const int b = q >> 13;

  if (t < GFN) poolm[t] = pool[b*GFN+t] * (1.0f / (float)N_PTS);
  __syncthreads();
  if (t < 20){
    float a = b3a[t];
    for (int c = 0; c < GFN; c++) a = fmaf(poolm[c], w3a[(GFN+c)*20+t], a);
    poolpart[t] = a;
  }
  __syncthreads();

  float acc[20];
  #pragma unroll
  for (int o = 0; o < 20; o++) acc[o] = 0.0f;
  #pragma unroll 4
  for (int c = 0; c < GFN; c++){
    float xv = x1t[(size_t)c*NQ + q];
    #pragma unroll
    for (int o = 0; o < 20; o++) acc[o] = fmaf(xv, w3a[c*20+o], acc[o]);
  }
  float o1[20];
  #pragma unroll
  for (int o = 0; o < 20; o++) o1[o] = fmaxf(acc[o] + poolpart[o], 0.0f);

  float o2[10];
  #pragma unroll
  for (int o = 0; o < 10; o++){
    float a = b3b[o];
    #pragma unroll
    for (int c = 0; c < 20; c++) a = fmaf(o1[c], w3b[c*10+o], a);
    o2[o] = fmaxf(a, 0.0f);
  }
  float e0 = b3c[0], e1 = b3c[1];
  #pragma unroll
  for (int c = 0; c < 10; c++){
    e0 = fmaf(o2[c], w3c[c*2+0], e0);
    e1 = fmaf(o2[c], w3c[c*2+1], e1);
  }
  float mx = fmaxf(e0, e1);
  float a0 = e0 - mx, a1 = e1 - mx;
  float lse = logf(expf(a0) + expf(a1));
  float2 r; r.x = a0 - lse; r.y = a1 - lse;
  *reinterpret_cast<float2*>(out + (size_t)q*2) = r;
}

extern "C" void kernel_launch(void* const* d_in, const int* in_sizes, int n_in,
                              void* d_out, int out_size, void* d_ws, size_t ws_size,
                              hipStream_t stream) {
  const float* x   = (const float*)d_in[0];
  const float* w1a = (const float*)d_in[1];
  const float* b1a = (const float*)d_in[2];
  const float* w1b = (const float*)d_in[3];
  const float* b1b = (const float*)d_in[4];
  const float* w2  = (const float*)d_in[5];
  const float* b2  = (const float*)d_in[6];
  const float* w3a = (const float*)d_in[7];
  const float* b3a = (const float*)d_in[8];
  const float* w3b = (const float*)d_in[9];
  const float* b3b = (const float*)d_in[10];
  const float* w3c = (const float*)d_in[11];
  const float* b3c = (const float*)d_in[12];
  float* out = (float*)d_out;

  char* ws = (char*)d_ws;
  float* cand = (float*)ws;                                        // NQ*NSPLIT*KNN fp32 (5.2 MB)
  float* x1t  = (float*)(ws + (size_t)NQ*NSPLIT*KNN*4);            // GFN*NQ fp32 (13.1 MB)
  float* pool = (float*)(ws + (size_t)NQ*NSPLIT*KNN*4
                            + (size_t)GFN*NQ*4);                   // NBATCH*GFN fp32

  zero_kernel<<<7, 64, 0, stream>>>(pool);
  knn_kernel<<<dim3(NQ/256, NSPLIT), 256, 0, stream>>>(x, cand);
  mlp1_kernel<<<NQ/256, 256, 0, stream>>>(x, cand, w1a, b1a, w1b, b1b, w2, b2, x1t, pool);
  head_kernel<<<NQ/256, 256, 0, stream>>>(x1t, pool, w3a, b3a, w3b, b3b, w3c, b3c, out);
}

// Round 2
// 346.473 us; speedup vs baseline: 1.3532x; 1.3532x over previous
//
#include <hip/hip_runtime.h>
#include <math.h>

#define N_PTS   8192
#define NBATCH  4
#define NQ      (N_PTS*NBATCH)   // 32768
#define GFN     100
#define KNN     10
#define NSPLIT  4
#define SPLITL  (N_PTS/NSPLIT)   // 2048
#define PTS_BLK 64

__device__ __forceinline__ float med3f(float a, float b, float c){
  return __builtin_amdgcn_fmed3f(a, b, c);
}

// sorted insert of d into ascending m[0..9], dropping the largest.
__device__ __forceinline__ void insert10(float (&m)[KNN], float d){
  #pragma unroll
  for (int k = KNN-1; k > 0; k--) m[k] = med3f(d, m[k-1], m[k]);
  m[0] = fminf(m[0], d);
}

__global__ void zero_kernel(float* __restrict__ pool){
  int i = blockIdx.x * 64 + threadIdx.x;
  if (i < NBATCH * GFN) pool[i] = 0.0f;
}

// ---------------- K1: KNN top-10 distances, 4-way split over j ----------------
__global__ __launch_bounds__(256) void knn_kernel(const float* __restrict__ x,
                                                  float* __restrict__ cand){
  __shared__ float4 tile[SPLITL];   // 32 KB: (x,y,z,sq) per staged point
  const int t  = threadIdx.x;
  const int qb = blockIdx.x;
  const int s  = blockIdx.y;
  const int q  = qb * 256 + t;
  const int b  = q >> 13;
  const float* xb = x + (size_t)b * N_PTS * 3;

  {
    const float4* src = reinterpret_cast<const float4*>(xb + (size_t)s * SPLITL * 3);
    float f[24];
    #pragma unroll
    for (int k = 0; k < 6; k++){
      float4 v = src[t*6 + k];
      f[4*k+0] = v.x; f[4*k+1] = v.y; f[4*k+2] = v.z; f[4*k+3] = v.w;
    }
    #pragma unroll
    for (int p = 0; p < 8; p++){
      float px = f[3*p+0], py = f[3*p+1], pz = f[3*p+2];
      float sq = fmaf(pz, pz, fmaf(py, py, px*px));
      tile[t*8 + p] = make_float4(px, py, pz, sq);
    }
  }
  __syncthreads();

  const float xi = x[(size_t)q*3+0], yi = x[(size_t)q*3+1], zi = x[(size_t)q*3+2];
  const float sqi = fmaf(zi, zi, fmaf(yi, yi, xi*xi));

  float m[KNN];
  #pragma unroll
  for (int k = 0; k < KNN; k++) m[k] = INFINITY;

  #pragma unroll 4
  for (int j = 0; j < SPLITL; j++){
    float4 p = tile[j];
    float dot = fmaf(zi, p.z, fmaf(yi, p.y, xi*p.x));
    float d   = fmaf(-2.0f, dot, sqi + p.w);
    if (d < m[KNN-1]) insert10(m, d);
  }

  float* outp = cand + (size_t)q * (NSPLIT*KNN) + s * KNN;
  #pragma unroll
  for (int k = 0; k < KNN; k++) outp[k] = m[k];
}

// ------------- K2: merge top-10, conv1 (13->20->100), conv2 (100->100) + pool -------------
// 64 points/block, 4 threads/point. Thread (p,g) computes channel chunk [g*25, g*25+25).
// Weight indices are wave-uniform (g in SGPR) -> scalar loads; VALU does only FMAs.
__global__ __launch_bounds__(256) void mlp1_kernel(
    const float* __restrict__ x,   const float* __restrict__ cand,
    const float* __restrict__ w1a, const float* __restrict__ b1a,
    const float* __restrict__ w1b, const float* __restrict__ b1b,
    const float* __restrict__ w2,  const float* __restrict__ b2,
    float* __restrict__ x1t, float* __restrict__ pool){
  __shared__ float t20s[PTS_BLK*21];    // stride 21: p*21 mod 32 covers all banks
  __shared__ float x1s[PTS_BLK*101];    // stride 101: same
  const int t = threadIdx.x;
  const int p = t & 63;
  const int g = __builtin_amdgcn_readfirstlane(t >> 6);  // wave-uniform 0..3
  const int q0 = blockIdx.x * PTS_BLK;
  const int q  = q0 + p;
  const int b  = q >> 13;

  // merge 4 sorted candidate lists -> global top-10 (redundant across g, cheap)
  float m[KNN];
  #pragma unroll
  for (int k = 0; k < KNN; k++) m[k] = INFINITY;
  const float* cp = cand + (size_t)q * (NSPLIT*KNN);
  #pragma unroll
  for (int i = 0; i < NSPLIT*KNN; i++) insert10(m, cp[i]);

  float h[13];
  h[0] = x[(size_t)q*3+0]; h[1] = x[(size_t)q*3+1]; h[2] = x[(size_t)q*3+2];
  #pragma unroll
  for (int k = 0; k < KNN; k++) h[3+k] = m[k];

  // phase A: t20 outputs o = g*5 + j
  {
    const float* wa = w1a + g*5;
    const float* ba = b1a + g*5;
    float a[5];
    #pragma unroll
    for (int j = 0; j < 5; j++) a[j] = ba[j];
    #pragma unroll
    for (int c = 0; c < 13; c++){
      float hv = h[c];
      #pragma unroll
      for (int j = 0; j < 5; j++) a[j] = fmaf(hv, wa[c*20+j], a[j]);
    }
    #pragma unroll
    for (int j = 0; j < 5; j++) t20s[p*21 + g*5 + j] = fmaxf(a[j], 0.0f);
  }
  __syncthreads();

  float acc[25];

  // phase B: x1 outputs o = g*25 + k
  {
    const float* wb = w1b + g*25;
    const float* bb = b1b + g*25;
    #pragma unroll
    for (int k = 0; k < 25; k++) acc[k] = bb[k];
    #pragma unroll 2
    for (int c = 0; c < 20; c++){
      float tv = t20s[p*21 + c];
      #pragma unroll
      for (int k = 0; k < 25; k++) acc[k] = fmaf(tv, wb[c*GFN+k], acc[k]);
    }
    #pragma unroll
    for (int k = 0; k < 25; k++){
      float v = fmaxf(acc[k], 0.0f);
      x1s[p*101 + g*25 + k] = v;
      x1t[(size_t)(g*25+k)*NQ + q] = v;   // coalesced: lanes p consecutive
    }
  }
  __syncthreads();

  // phase C: x2 outputs o = g*25 + k, then pool reduction
  {
    const float* wc = w2 + g*25;
    const float* bc = b2 + g*25;
    #pragma unroll
    for (int k = 0; k < 25; k++) acc[k] = bc[k];
    #pragma unroll 2
    for (int c = 0; c < GFN; c++){
      float xv = x1s[p*101 + c];
      #pragma unroll
      for (int k = 0; k < 25; k++) acc[k] = fmaf(xv, wc[c*GFN+k], acc[k]);
    }
    #pragma unroll
    for (int k = 0; k < 25; k++){
      float v = fmaxf(acc[k], 0.0f);
      #pragma unroll
      for (int off = 1; off < 64; off <<= 1) v += __shfl_xor(v, off);
      if (p == 0) atomicAdd(&pool[b*GFN + g*25 + k], v);
    }
  }
}

// ---------------- K3: head (200->20->10->2) + log_softmax ----------------
__global__ __launch_bounds__(128) void head_kernel(
    const float* __restrict__ x1t, const float* __restrict__ pool,
    const float* __restrict__ w3a, const float* __restrict__ b3a,
    const float* __restrict__ w3b, const float* __restrict__ b3b,
    const float* __restrict__ w3c, const float* __restrict__ b3c,
    float* __restrict__ out){
  __shared__ float poolm[GFN];
  __shared__ float poolpart[20];
  const int t = threadIdx.x;
  const int q = blockIdx.x * 128 + t;
  const int b = q >> 13;

  if (t < GFN) poolm[t] = pool[b*GFN+t] * (1.0f / (float)N_PTS);
  __syncthreads();
  if (t < 20){
    float a = b3a[t];
    for (int c = 0; c < GFN; c++) a = fmaf(poolm[c], w3a[(GFN+c)*20+t], a);
    poolpart[t] = a;
  }
  __syncthreads();

  float acc[20];
  #pragma unroll
  for (int o = 0; o < 20; o++) acc[o] = 0.0f;
  #pragma unroll 4
  for (int c = 0; c < GFN; c++){
    float xv = x1t[(size_t)c*NQ + q];
    #pragma unroll
    for (int o = 0; o < 20; o++) acc[o] = fmaf(xv, w3a[c*20+o], acc[o]);
  }
  float o1[20];
  #pragma unroll
  for (int o = 0; o < 20; o++) o1[o] = fmaxf(acc[o] + poolpart[o], 0.0f);

  float o2[10];
  #pragma unroll
  for (int o = 0; o < 10; o++){
    float a = b3b[o];
    #pragma unroll
    for (int c = 0; c < 20; c++) a = fmaf(o1[c], w3b[c*10+o], a);
    o2[o] = fmaxf(a, 0.0f);
  }
  float e0 = b3c[0], e1 = b3c[1];
  #pragma unroll
  for (int c = 0; c < 10; c++){
    e0 = fmaf(o2[c], w3c[c*2+0], e0);
    e1 = fmaf(o2[c], w3c[c*2+1], e1);
  }
  float mx = fmaxf(e0, e1);
  float a0 = e0 - mx, a1 = e1 - mx;
  float lse = logf(expf(a0) + expf(a1));
  float2 r; r.x = a0 - lse; r.y = a1 - lse;
  *reinterpret_cast<float2*>(out + (size_t)q*2) = r;
}

extern "C" void kernel_launch(void* const* d_in, const int* in_sizes, int n_in,
                              void* d_out, int out_size, void* d_ws, size_t ws_size,
                              hipStream_t stream) {
  const float* x   = (const float*)d_in[0];
  const float* w1a = (const float*)d_in[1];
  const float* b1a = (const float*)d_in[2];
  const float* w1b = (const float*)d_in[3];
  const float* b1b = (const float*)d_in[4];
  const float* w2  = (const float*)d_in[5];
  const float* b2  = (const float*)d_in[6];
  const float* w3a = (const float*)d_in[7];
  const float* b3a = (const float*)d_in[8];
  const float* w3b = (const float*)d_in[9];
  const float* b3b = (const float*)d_in[10];
  const float* w3c = (const float*)d_in[11];
  const float* b3c = (const float*)d_in[12];
  float* out = (float*)d_out;

  char* ws = (char*)d_ws;
  float* cand = (float*)ws;                                        // NQ*NSPLIT*KNN fp32 (5.2 MB)
  float* x1t  = (float*)(ws + (size_t)NQ*NSPLIT*KNN*4);            // GFN*NQ fp32 (13.1 MB)
  float* pool = (float*)(ws + (size_t)NQ*NSPLIT*KNN*4
                            + (size_t)GFN*NQ*4);                   // NBATCH*GFN fp32

  zero_kernel<<<7, 64, 0, stream>>>(pool);
  knn_kernel<<<dim3(NQ/256, NSPLIT), 256, 0, stream>>>(x, cand);
  mlp1_kernel<<<NQ/PTS_BLK, 256, 0, stream>>>(x, cand, w1a, b1a, w1b, b1b, w2, b2, x1t, pool);
  head_kernel<<<NQ/128, 128, 0, stream>>>(x1t, pool, w3a, b3a, w3b, b3b, w3c, b3c, out);
}

// Round 3
// 322.565 us; speedup vs baseline: 1.4535x; 1.0741x over previous
//
#include <hip/hip_runtime.h>
#include <math.h>

#define N_PTS   8192
#define NBATCH  4
#define NQ      (N_PTS*NBATCH)   // 32768
#define GFN     100
#define KNN     10
#define NSPLIT  8
#define SPLITL  (N_PTS/NSPLIT)   // 1024
#define PTS_BLK 64
#define CH      13               // channels per group in mlp1 (8 groups, last has 9)

__device__ __forceinline__ float med3f(float a, float b, float c){
  return __builtin_amdgcn_fmed3f(a, b, c);
}

// sorted insert of d into ascending m[0..9], dropping the largest.
// All 10 med3 are independent (each reads pre-insert values) -> issue-bound.
// If d >= m[9] the whole chain is a no-op, so unconditional use is correct.
__device__ __forceinline__ void insert10(float (&m)[KNN], float d){
  #pragma unroll
  for (int k = KNN-1; k > 0; k--) m[k] = med3f(d, m[k-1], m[k]);
  m[0] = fminf(m[0], d);
}

// ---------------- K1: KNN top-10 distances, 8-way split over j ----------------
// Branchless insert, conflict-free staging, coalesced cand[(s*10+k)*NQ + q].
__global__ __launch_bounds__(256) void knn_kernel(const float* __restrict__ x,
                                                  float* __restrict__ cand,
                                                  float* __restrict__ pool){
  __shared__ float4 tile[SPLITL];   // 16 KB: (x,y,z,sq) per staged point
  const int t  = threadIdx.x;
  const int qb = blockIdx.x;
  const int s  = blockIdx.y;
  const int q  = qb * 256 + t;
  const int b  = q >> 13;
  const float* xb = x + (size_t)b * N_PTS * 3;

  // fold pool zeroing into this kernel (one block does it)
  if (qb == 0 && s == 0){
    for (int i = t; i < NBATCH*GFN; i += 256) pool[i] = 0.0f;
  }

  // stage 1024 points: thread t writes points {t, t+256, t+512, t+768}
  // -> lane-consecutive float4 writes (conflict-free)
  #pragma unroll
  for (int k = 0; k < 4; k++){
    const int j = t + 256*k;
    const float* ps = xb + (size_t)(s*SPLITL + j)*3;
    float px = ps[0], py = ps[1], pz = ps[2];
    float sq = fmaf(pz, pz, fmaf(py, py, px*px));
    tile[j] = make_float4(px, py, pz, sq);
  }
  __syncthreads();

  const float xi = x[(size_t)q*3+0], yi = x[(size_t)q*3+1], zi = x[(size_t)q*3+2];
  const float sqi = fmaf(zi, zi, fmaf(yi, yi, xi*xi));

  float m[KNN];
  #pragma unroll
  for (int k = 0; k < KNN; k++) m[k] = INFINITY;

  #pragma unroll 8
  for (int j = 0; j < SPLITL; j++){
    float4 p = tile[j];
    float dot = fmaf(zi, p.z, fmaf(yi, p.y, xi*p.x));
    float d   = fmaf(-2.0f, dot, sqi + p.w);
    insert10(m, d);              // branchless
  }

  // transposed candidate layout: cand[(s*10+k)*NQ + q] -> coalesced stores & loads
  #pragma unroll
  for (int k = 0; k < KNN; k++) cand[(size_t)(s*KNN + k)*NQ + q] = m[k];
}

// ------------- K2: merge top-10, conv1 (13->20->100), conv2 (100->100) + pool -------------
// 64 points/block, 512 threads = 8 waves. Wave g handles channel chunk [g*13, g*13+13)∩[0,100).
// 16 waves/CU for latency hiding of the s_load weight stream.
__global__ __launch_bounds__(512) void mlp1_kernel(
    const float* __restrict__ x,   const float* __restrict__ cand,
    const float* __restrict__ w1a, const float* __restrict__ b1a,
    const float* __restrict__ w1b, const float* __restrict__ b1b,
    const float* __restrict__ w2,  const float* __restrict__ b2,
    float* __restrict__ x1t, float* __restrict__ pool){
  __shared__ float t20s[PTS_BLK*21];    // stride 21: conflict-free
  __shared__ float x1s[PTS_BLK*101];    // stride 101: conflict-free
  const int t = threadIdx.x;
  const int p = t & 63;
  const int g = __builtin_amdgcn_readfirstlane(t >> 6);  // wave-uniform 0..7
  const int q0 = blockIdx.x * PTS_BLK;
  const int q  = q0 + p;
  const int b  = q >> 13;

  // phase A: t20 (13->20), done by waves g<4 (5 outputs each)
  if (g < 4){
    // merge 8 sorted candidate lists -> global top-10 (coalesced reads)
    float m[KNN];
    #pragma unroll
    for (int k = 0; k < KNN; k++) m[k] = INFINITY;
    #pragma unroll
    for (int i = 0; i < NSPLIT*KNN; i++) insert10(m, cand[(size_t)i*NQ + q]);

    float h[13];
    h[0] = x[(size_t)q*3+0]; h[1] = x[(size_t)q*3+1]; h[2] = x[(size_t)q*3+2];
    #pragma unroll
    for (int k = 0; k < KNN; k++) h[3+k] = m[k];

    const float* wa = w1a + g*5;
    float a[5];
    #pragma unroll
    for (int j = 0; j < 5; j++) a[j] = b1a[g*5+j];
    #pragma unroll
    for (int c = 0; c < 13; c++){
      float hv = h[c];
      #pragma unroll
      for (int j = 0; j < 5; j++) a[j] = fmaf(hv, wa[c*20+j], a[j]);
    }
    #pragma unroll
    for (int j = 0; j < 5; j++) t20s[p*21 + g*5 + j] = fmaxf(a[j], 0.0f);
  }
  __syncthreads();

  float acc[CH];
  const int o0 = g * CH;

  // phase B: x1 (20->100), outputs o = o0+k (masked to <100)
  {
    #pragma unroll
    for (int k = 0; k < CH; k++) acc[k] = (o0+k < GFN) ? b1b[o0+k] : 0.0f;
    #pragma unroll 4
    for (int c = 0; c < 20; c++){
      float tv = t20s[p*21 + c];
      #pragma unroll
      for (int k = 0; k < CH; k++)
        if (o0+k < GFN) acc[k] = fmaf(tv, w1b[c*GFN + o0+k], acc[k]);
    }
    #pragma unroll
    for (int k = 0; k < CH; k++){
      if (o0+k < GFN){
        float v = fmaxf(acc[k], 0.0f);
        x1s[p*101 + o0+k] = v;
        x1t[(size_t)(o0+k)*NQ + q] = v;   // coalesced
      }
    }
  }
  __syncthreads();

  // phase C: x2 (100->100) + pool reduce
  {
    #pragma unroll
    for (int k = 0; k < CH; k++) acc[k] = (o0+k < GFN) ? b2[o0+k] : 0.0f;
    #pragma unroll 4
    for (int c = 0; c < GFN; c++){
      float xv = x1s[p*101 + c];
      #pragma unroll
      for (int k = 0; k < CH; k++)
        if (o0+k < GFN) acc[k] = fmaf(xv, w2[c*GFN + o0+k], acc[k]);
    }
    #pragma unroll
    for (int k = 0; k < CH; k++){
      if (o0+k < GFN){
        float v = fmaxf(acc[k], 0.0f);
        #pragma unroll
        for (int off = 1; off < 64; off <<= 1) v += __shfl_xor(v, off);
        if (p == 0) atomicAdd(&pool[b*GFN + o0+k], v);
      }
    }
  }
}

// ---------------- K3: head (200->20->10->2) + log_softmax ----------------
__global__ __launch_bounds__(128) void head_kernel(
    const float* __restrict__ x1t, const float* __restrict__ pool,
    const float* __restrict__ w3a, const float* __restrict__ b3a,
    const float* __restrict__ w3b, const float* __restrict__ b3b,
    const float* __restrict__ w3c, const float* __restrict__ b3c,
    float* __restrict__ out){
  __shared__ float poolm[GFN];
  __shared__ float poolpart[20];
  const int t = threadIdx.x;
  const int q = blockIdx.x * 128 + t;
  const int b = q >> 13;

  if (t < GFN) poolm[t] = pool[b*GFN+t] * (1.0f / (float)N_PTS);
  __syncthreads();
  if (t < 20){
    float a = b3a[t];
    for (int c = 0; c < GFN; c++) a = fmaf(poolm[c], w3a[(GFN+c)*20+t], a);
    poolpart[t] = a;
  }
  __syncthreads();

  float acc[20];
  #pragma unroll
  for (int o = 0; o < 20; o++) acc[o] = 0.0f;
  #pragma unroll 8
  for (int c = 0; c < GFN; c++){
    float xv = x1t[(size_t)c*NQ + q];
    #pragma unroll
    for (int o = 0; o < 20; o++) acc[o] = fmaf(xv, w3a[c*20+o], acc[o]);
  }
  float o1[20];
  #pragma unroll
  for (int o = 0; o < 20; o++) o1[o] = fmaxf(acc[o] + poolpart[o], 0.0f);

  float o2[10];
  #pragma unroll
  for (int o = 0; o < 10; o++){
    float a = b3b[o];
    #pragma unroll
    for (int c = 0; c < 20; c++) a = fmaf(o1[c], w3b[c*10+o], a);
    o2[o] = fmaxf(a, 0.0f);
  }
  float e0 = b3c[0], e1 = b3c[1];
  #pragma unroll
  for (int c = 0; c < 10; c++){
    e0 = fmaf(o2[c], w3c[c*2+0], e0);
    e1 = fmaf(o2[c], w3c[c*2+1], e1);
  }
  float mx = fmaxf(e0, e1);
  float a0 = e0 - mx, a1 = e1 - mx;
  float lse = logf(expf(a0) + expf(a1));
  float2 r; r.x = a0 - lse; r.y = a1 - lse;
  *reinterpret_cast<float2*>(out + (size_t)q*2) = r;
}

extern "C" void kernel_launch(void* const* d_in, const int* in_sizes, int n_in,
                              void* d_out, int out_size, void* d_ws, size_t ws_size,
                              hipStream_t stream) {
  const float* x   = (const float*)d_in[0];
  const float* w1a = (const float*)d_in[1];
  const float* b1a = (const float*)d_in[2];
  const float* w1b = (const float*)d_in[3];
  const float* b1b = (const float*)d_in[4];
  const float* w2  = (const float*)d_in[5];
  const float* b2  = (const float*)d_in[6];
  const float* w3a = (const float*)d_in[7];
  const float* b3a = (const float*)d_in[8];
  const float* w3b = (const float*)d_in[9];
  const float* b3b = (const float*)d_in[10];
  const float* w3c = (const float*)d_in[11];
  const float* b3c = (const float*)d_in[12];
  float* out = (float*)d_out;

  char* ws = (char*)d_ws;
  float* cand = (float*)ws;                                        // NSPLIT*KNN*NQ fp32 (10.5 MB)
  float* x1t  = (float*)(ws + (size_t)NQ*NSPLIT*KNN*4);            // GFN*NQ fp32 (13.1 MB)
  float* pool = (float*)(ws + (size_t)NQ*NSPLIT*KNN*4
                            + (size_t)GFN*NQ*4);                   // NBATCH*GFN fp32

  knn_kernel<<<dim3(NQ/256, NSPLIT), 256, 0, stream>>>(x, cand, pool);
  mlp1_kernel<<<NQ/PTS_BLK, 512, 0, stream>>>(x, cand, w1a, b1a, w1b, b1b, w2, b2, x1t, pool);
  head_kernel<<<NQ/128, 128, 0, stream>>>(x1t, pool, w3a, b3a, w3b, b3b, w3c, b3c, out);
}

// Round 4
// 273.264 us; speedup vs baseline: 1.7158x; 1.1804x over previous
//
#include <hip/hip_runtime.h>
#include <math.h>

#define N_PTS   8192
#define NBATCH  4
#define NQ      (N_PTS*NBATCH)   // 32768
#define GFN     100
#define KNN     10
#define NSPLIT  8
#define SPLITL  (N_PTS/NSPLIT)   // 1024
#define MBLK    128              // points per mlp1 block
#define CHK     25               // channels per wave (4 waves * 25 = 100, exact)

__device__ __forceinline__ float med3f(float a, float b, float c){
  return __builtin_amdgcn_fmed3f(a, b, c);
}

// sorted insert of d into ascending m[0..9], dropping the largest.
__device__ __forceinline__ void insert10(float (&m)[KNN], float d){
  #pragma unroll
  for (int k = KNN-1; k > 0; k--) m[k] = med3f(d, m[k-1], m[k]);
  m[0] = fminf(m[0], d);
}

// ---------------- K1: KNN top-10 distances, 8-way split over j ----------------
__global__ __launch_bounds__(256) void knn_kernel(const float* __restrict__ x,
                                                  float* __restrict__ cand,
                                                  float* __restrict__ pool){
  __shared__ float4 tile[SPLITL];   // 16 KB
  const int t  = threadIdx.x;
  const int qb = blockIdx.x;
  const int s  = blockIdx.y;
  const int q  = qb * 256 + t;
  const int b  = q >> 13;
  const float* xb = x + (size_t)b * N_PTS * 3;

  if (qb == 0 && s == 0){
    for (int i = t; i < NBATCH*GFN; i += 256) pool[i] = 0.0f;
  }

  #pragma unroll
  for (int k = 0; k < 4; k++){
    const int j = t + 256*k;
    const float* ps = xb + (size_t)(s*SPLITL + j)*3;
    float px = ps[0], py = ps[1], pz = ps[2];
    float sq = fmaf(pz, pz, fmaf(py, py, px*px));
    tile[j] = make_float4(px, py, pz, sq);
  }
  __syncthreads();

  const float xi = x[(size_t)q*3+0], yi = x[(size_t)q*3+1], zi = x[(size_t)q*3+2];
  const float sqi = fmaf(zi, zi, fmaf(yi, yi, xi*xi));

  float m[KNN];
  #pragma unroll
  for (int k = 0; k < KNN; k++) m[k] = INFINITY;

  #pragma unroll 8
  for (int j = 0; j < SPLITL; j++){
    float4 p = tile[j];
    float dot = fmaf(zi, p.z, fmaf(yi, p.y, xi*p.x));
    float d   = fmaf(-2.0f, dot, sqi + p.w);   // matches (sqi+sqj) - 2*dot rounding
    insert10(m, d);              // branchless
  }

  #pragma unroll
  for (int k = 0; k < KNN; k++) cand[(size_t)(s*KNN + k)*NQ + q] = m[k];
}

// ------------- K2: merge, conv1 (13->20->100), conv2 (100->100) + pool -------------
// 256 threads = 4 waves; block owns 128 points. Wave g computes channels
// [g*25, g*25+25) for 2 points per lane (p and p+64). All register indices
// compile-time; weight addresses wave-uniform -> SGPR s_load; 2 FMA per weight.
__global__ __launch_bounds__(256) void mlp1_kernel(
    const float* __restrict__ x,   const float* __restrict__ cand,
    const float* __restrict__ w1a, const float* __restrict__ b1a,
    const float* __restrict__ w1b, const float* __restrict__ b1b,
    const float* __restrict__ w2,  const float* __restrict__ b2,
    float* __restrict__ x1t, float* __restrict__ pool){
  __shared__ float t20s[MBLK*21];    // 10.75 KB, stride 21 conflict-free
  __shared__ float x1s[MBLK*101];    // 51.7 KB, stride 101 conflict-free
  const int t = threadIdx.x;
  const int p = t & 63;
  const int g = __builtin_amdgcn_readfirstlane(t >> 6);  // 0..3
  const int q0 = blockIdx.x * MBLK;
  const int b  = q0 >> 13;           // whole block in one batch (8192 % 128 == 0)

  // ---- phase A: waves 0,1 each do the front-end for 64 points ----
  if (g < 2){
    const int pr = g*64 + p;         // point row in block
    const int q  = q0 + pr;
    float m[KNN];
    #pragma unroll
    for (int k = 0; k < KNN; k++) m[k] = INFINITY;
    #pragma unroll
    for (int i = 0; i < NSPLIT*KNN; i++) insert10(m, cand[(size_t)i*NQ + q]);

    float h[13];
    h[0] = x[(size_t)q*3+0]; h[1] = x[(size_t)q*3+1]; h[2] = x[(size_t)q*3+2];
    #pragma unroll
    for (int k = 0; k < KNN; k++) h[3+k] = m[k];

    float a[20];
    #pragma unroll
    for (int o = 0; o < 20; o++) a[o] = b1a[o];
    #pragma unroll
    for (int c = 0; c < 13; c++){
      float hv = h[c];
      #pragma unroll
      for (int o = 0; o < 20; o++) a[o] = fmaf(hv, w1a[c*20+o], a[o]);
    }
    #pragma unroll
    for (int o = 0; o < 20; o++) t20s[pr*21 + o] = fmaxf(a[o], 0.0f);
  }
  __syncthreads();

  const int o0 = g * CHK;
  float accA[CHK], accB[CHK];

  // ---- phase B: x1 = relu(t20 @ w1b + b1b), 2 points/thread ----
  #pragma unroll
  for (int k = 0; k < CHK; k++){ float bv = b1b[o0+k]; accA[k] = bv; accB[k] = bv; }
  #pragma unroll 4
  for (int c = 0; c < 20; c++){
    float ta = t20s[p*21 + c];
    float tb = t20s[(64+p)*21 + c];
    #pragma unroll
    for (int k = 0; k < CHK; k++){
      float w = w1b[c*GFN + o0 + k];
      accA[k] = fmaf(ta, w, accA[k]);
      accB[k] = fmaf(tb, w, accB[k]);
    }
  }
  #pragma unroll
  for (int k = 0; k < CHK; k++){
    float va = fmaxf(accA[k], 0.0f);
    float vb = fmaxf(accB[k], 0.0f);
    x1s[p*101 + o0 + k] = va;
    x1s[(64+p)*101 + o0 + k] = vb;
    x1t[(size_t)(o0+k)*NQ + q0 + p]      = va;   // coalesced
    x1t[(size_t)(o0+k)*NQ + q0 + 64 + p] = vb;
  }
  __syncthreads();

  // ---- phase C: x2 = relu(x1 @ w2 + b2), then pool reduce ----
  #pragma unroll
  for (int k = 0; k < CHK; k++){ float bv = b2[o0+k]; accA[k] = bv; accB[k] = bv; }
  #pragma unroll 4
  for (int c = 0; c < GFN; c++){
    float xa = x1s[p*101 + c];
    float xb = x1s[(64+p)*101 + c];
    #pragma unroll
    for (int k = 0; k < CHK; k++){
      float w = w2[c*GFN + o0 + k];
      accA[k] = fmaf(xa, w, accA[k]);
      accB[k] = fmaf(xb, w, accB[k]);
    }
  }
  #pragma unroll
  for (int k = 0; k < CHK; k++){
    float va = fmaxf(accA[k], 0.0f);
    float vb = fmaxf(accB[k], 0.0f);
    #pragma unroll
    for (int off = 1; off < 64; off <<= 1){
      va += __shfl_xor(va, off);
      vb += __shfl_xor(vb, off);
    }
    if (p == 0){
      atomicAdd(&pool[b*GFN + o0 + k], va);
      atomicAdd(&pool[b*GFN + o0 + k], vb);
    }
  }
}

// ---------------- K3: head (200->20->10->2) + log_softmax ----------------
__global__ __launch_bounds__(128) void head_kernel(
    const float* __restrict__ x1t, const float* __restrict__ pool,
    const float* __restrict__ w3a, const float* __restrict__ b3a,
    const float* __restrict__ w3b, const float* __restrict__ b3b,
    const float* __restrict__ w3c, const float* __restrict__ b3c,
    float* __restrict__ out){
  __shared__ float poolm[GFN];
  __shared__ float poolpart[20];
  const int t = threadIdx.x;
  const int q = blockIdx.x * 128 + t;
  const int b = q >> 13;

  if (t < GFN) poolm[t] = pool[b*GFN+t] * (1.0f / (float)N_PTS);
  __syncthreads();
  if (t < 20){
    float a = b3a[t];
    for (int c = 0; c < GFN; c++) a = fmaf(poolm[c], w3a[(GFN+c)*20+t], a);
    poolpart[t] = a;
  }
  __syncthreads();

  float acc[20];
  #pragma unroll
  for (int o = 0; o < 20; o++) acc[o] = 0.0f;
  #pragma unroll 8
  for (int c = 0; c < GFN; c++){
    float xv = x1t[(size_t)c*NQ + q];
    #pragma unroll
    for (int o = 0; o < 20; o++) acc[o] = fmaf(xv, w3a[c*20+o], acc[o]);
  }
  float o1[20];
  #pragma unroll
  for (int o = 0; o < 20; o++) o1[o] = fmaxf(acc[o] + poolpart[o], 0.0f);

  float o2[10];
  #pragma unroll
  for (int o = 0; o < 10; o++){
    float a = b3b[o];
    #pragma unroll
    for (int c = 0; c < 20; c++) a = fmaf(o1[c], w3b[c*10+o], a);
    o2[o] = fmaxf(a, 0.0f);
  }
  float e0 = b3c[0], e1 = b3c[1];
  #pragma unroll
  for (int c = 0; c < 10; c++){
    e0 = fmaf(o2[c], w3c[c*2+0], e0);
    e1 = fmaf(o2[c], w3c[c*2+1], e1);
  }
  float mx = fmaxf(e0, e1);
  float a0 = e0 - mx, a1 = e1 - mx;
  float lse = logf(expf(a0) + expf(a1));
  float2 r; r.x = a0 - lse; r.y = a1 - lse;
  *reinterpret_cast<float2*>(out + (size_t)q*2) = r;
}

extern "C" void kernel_launch(void* const* d_in, const int* in_sizes, int n_in,
                              void* d_out, int out_size, void* d_ws, size_t ws_size,
                              hipStream_t stream) {
  const float* x   = (const float*)d_in[0];
  const float* w1a = (const float*)d_in[1];
  const float* b1a = (const float*)d_in[2];
  const float* w1b = (const float*)d_in[3];
  const float* b1b = (const float*)d_in[4];
  const float* w2  = (const float*)d_in[5];
  const float* b2  = (const float*)d_in[6];
  const float* w3a = (const float*)d_in[7];
  const float* b3a = (const float*)d_in[8];
  const float* w3b = (const float*)d_in[9];
  const float* b3b = (const float*)d_in[10];
  const float* w3c = (const float*)d_in[11];
  const float* b3c = (const float*)d_in[12];
  float* out = (float*)d_out;

  char* ws = (char*)d_ws;
  float* cand = (float*)ws;                                        // NSPLIT*KNN*NQ fp32 (10.5 MB)
  float* x1t  = (float*)(ws + (size_t)NQ*NSPLIT*KNN*4);            // GFN*NQ fp32 (13.1 MB)
  float* pool = (float*)(ws + (size_t)NQ*NSPLIT*KNN*4
                            + (size_t)GFN*NQ*4);                   // NBATCH*GFN fp32

  knn_kernel<<<dim3(NQ/256, NSPLIT), 256, 0, stream>>>(x, cand, pool);
  mlp1_kernel<<<NQ/MBLK, 256, 0, stream>>>(x, cand, w1a, b1a, w1b, b1b, w2, b2, x1t, pool);
  head_kernel<<<NQ/128, 128, 0, stream>>>(x1t, pool, w3a, b3a, w3b, b3b, w3c, b3c, out);
}